// Round 6
// baseline (1379.555 us; speedup 1.0000x reference)
//
#include <hip/hip_runtime.h>
#include <hip/hip_cooperative_groups.h>
#include <math.h>

namespace cg = cooperative_groups;

// OFPenalty round 6: register-resident A. One cooperative kernel (256x1024,
// the shape certified by round 5). Each thread permanently holds 24 float4
// (96 floats) of its (row, slice) of A in VGPRs; the 16 tail floats per row
// live in LDS. A is read from HBM exactly ONCE; all 12 matvec phases run
// from registers + LDS. Round-5 lesson: re-reading A is latency-bound at
// 1 block/CU (VALUBusy 3.6%, HBM 12.5%) and L3 is poison-evicted each run.
// A: (64, 512, 28, 28) fp32 -> W: (64, 512, 784). x0: (64, 512, 1).

#define BB 64
#define CC 512
#define DD 784
#define NBLK 256
#define TPB  1024
#define RPB  128           // rows per block (4 blocks per batch)
#define FEPS 1e-12f

// acc[b*4+0]=largest, +1=dotwx, +2=den2 (1,2 atomic; all zeroed in-kernel)

__device__ __forceinline__ float blk_reduce16(float s, float* red) {
    for (int off = 32; off; off >>= 1) s += __shfl_down(s, off, 64);
    int w = threadIdx.x >> 6;
    if ((threadIdx.x & 63) == 0) red[w] = s;
    __syncthreads();
    float t = 0.0f;
#pragma unroll
    for (int i = 0; i < 16; i++) t += red[i];
    __syncthreads();
    return t;
}

__global__ __launch_bounds__(TPB, 4)
void c_all(const float* __restrict__ A, const float* __restrict__ x0,
           float* __restrict__ out, float* __restrict__ ws) {
    __shared__ float4 stg[16 * 196];     // 50176 B load-staging (16 rows)
    __shared__ float4 u_pad4[204];       // 816 floats: 8 slices x 100 + 16 tail
    __shared__ float  tailA[RPB * 16];   // 8192 B: last 16 floats of each row
    __shared__ float  red[16];
    float* u_pad = (float*)u_pad4;
    cg::grid_group grid = cg::this_grid();

    const int tid = threadIdx.x;
    const int b = blockIdx.x >> 2;          // batch
    const int stripe = blockIdx.x & 3;
    const int c0 = stripe * RPB;
    const int r = tid >> 3;                 // row_local 0..127
    const int s = tid & 7;                  // slice 0..7 (96 floats each)
    const int c = c0 + r;                   // global row in batch
    const int off3 = 3 * (r & 7);           // bank stagger for phase_u

    float* acc  = ws;                       // 256 floats
    float* ubuf = ws + 256;                 // 6 x BB*DD
    float* tbuf = ws + 256 + 6 * BB * DD;   // 7 x BB*CC

    // ---- zero atomic-accumulated globals (acc + u bufs)
    for (int i = blockIdx.x * TPB + tid; i < 256 + 6 * BB * DD; i += NBLK * TPB)
        ws[i] = 0.0f;

    // ---- load stripe into registers (st) + LDS tail, via coalesced staging
    const float4* Af4 = (const float4*)(A + ((size_t)b * CC + c0) * DD);
    float4 st[24];
    const int mych = r >> 4;                // which 16-row chunk owns my row
    for (int k = 0; k < 8; k++) {
        const float4* src = Af4 + (size_t)k * 16 * 196;
        for (int i = tid; i < 16 * 196; i += TPB) stg[i] = src[i];
        __syncthreads();
        if (mych == k) {
            int lr = r & 15;
#pragma unroll
            for (int kk = 0; kk < 24; kk++) {
                int ip = kk + off3; if (ip >= 24) ip -= 24;
                st[kk] = stg[lr * 196 + s * 24 + ip];
            }
            const float* sf = (const float*)stg;
            tailA[r * 16 + s * 2]     = sf[lr * 784 + 768 + s * 2];
            tailA[r * 16 + s * 2 + 1] = sf[lr * 784 + 768 + s * 2 + 1];
        }
        __syncthreads();
    }
    grid.sync();

    const float ta0 = tailA[r * 16 + s * 2];
    const float ta1 = tailA[r * 16 + s * 2 + 1];

    // ---- fused double-matvec: tn = AAT * normalize(xg), from registers.
    // mode 1: also dotwx += <v, xhat>, den2 += |xhat|^2 into s0/s1.
    auto dmv = [&](const float* xg, float* ug, float* tn, int mode,
                   float* s0, float* s1) {
        // normalize input (redundant per block, L2-hot)
        float xv = (tid < CC) ? xg[tid] : 0.0f;
        float ssv = blk_reduce16(xv * xv, red);
        float rn = 1.0f / fmaxf(sqrtf(ssv), FEPS);
        float xc = xg[c] * rn;              // my row's xhat (8 lanes share)
        // zero LDS u accumulator
        if (tid < 816) u_pad[tid] = 0.0f;
        __syncthreads();
        // phase_u: u_pad[d] += A[c,d] * xc  (staggered, bank-spread atomics)
#pragma unroll
        for (int kk = 0; kk < 24; kk++) {
            int ip = kk + off3; if (ip >= 24) ip -= 24;
            float4 a = st[kk];
            float* up = &u_pad[s * 100 + 4 * ip];
            atomicAdd(up + 0, a.x * xc);
            atomicAdd(up + 1, a.y * xc);
            atomicAdd(up + 2, a.z * xc);
            atomicAdd(up + 3, a.w * xc);
        }
        atomicAdd(&u_pad[800 + s * 2],     ta0 * xc);
        atomicAdd(&u_pad[800 + s * 2 + 1], ta1 * xc);
        __syncthreads();
        // dump block-partial u to global (4 blocks per batch accumulate)
        if (tid < 768)      atomicAdd(&ug[tid], u_pad[(tid / 96) * 100 + tid % 96]);
        else if (tid < 784) atomicAdd(&ug[tid], u_pad[800 + tid - 768]);
        grid.sync();
        // stage full u back into LDS
        if (tid < 768)      u_pad[(tid / 96) * 100 + tid % 96] = ug[tid];
        else if (tid < 784) u_pad[800 + tid - 768] = ug[tid];
        __syncthreads();
        // phase_v: v_c = <A[c,:], u>  (regs x LDS, xor-reduce over 8 slices)
        float vacc = ta0 * u_pad[800 + s * 2] + ta1 * u_pad[800 + s * 2 + 1];
#pragma unroll
        for (int kk = 0; kk < 24; kk++) {
            int ip = kk + off3; if (ip >= 24) ip -= 24;
            float4 a = st[kk];
            float4 u = u_pad4[s * 25 + ip];
            vacc += a.x * u.x + a.y * u.y + a.z * u.z + a.w * u.w;
        }
        vacc += __shfl_xor(vacc, 1);
        vacc += __shfl_xor(vacc, 2);
        vacc += __shfl_xor(vacc, 4);
        if (s == 0) tn[c] = vacc;
        if (mode) {
            float p0 = (s == 0) ? vacc * xc : 0.0f;
            float p1 = (s == 0) ? xc * xc : 0.0f;
            float P0 = blk_reduce16(p0, red);
            float P1 = blk_reduce16(p1, red);
            if (tid == 0) { atomicAdd(s0, P0); atomicAdd(s1, P1); }
        }
        grid.sync();
    };

    const float* x0b = x0 + (size_t)b * CC;
    float* T0 = tbuf + 0 * BB * CC + (size_t)b * CC;
    float* T1 = tbuf + 1 * BB * CC + (size_t)b * CC;
    float* T2 = tbuf + 2 * BB * CC + (size_t)b * CC;
    float* T3 = tbuf + 3 * BB * CC + (size_t)b * CC;  // unnormalized x1
    float* T4 = tbuf + 4 * BB * CC + (size_t)b * CC;  // AAT x1
    float* Y  = tbuf + 5 * BB * CC + (size_t)b * CC;  // unnormalized x2
    float* Wb = tbuf + 6 * BB * CC + (size_t)b * CC;  // AAT x2 (unused value)
    float* U0 = ubuf + 0 * BB * DD + (size_t)b * DD;
    float* U1 = ubuf + 1 * BB * DD + (size_t)b * DD;
    float* U2 = ubuf + 2 * BB * DD + (size_t)b * DD;
    float* U3 = ubuf + 3 * BB * DD + (size_t)b * DD;
    float* U4 = ubuf + 4 * BB * DD + (size_t)b * DD;
    float* U5 = ubuf + 5 * BB * DD + (size_t)b * DD;

    // 3 no-grad power steps + 1 differentiable step (t3 = unnorm x1)
    dmv(x0b, U0, T0, 0, nullptr, nullptr);
    dmv(T0,  U1, T1, 0, nullptr, nullptr);
    dmv(T1,  U2, T2, 0, nullptr, nullptr);
    dmv(T2,  U3, T3, 0, nullptr, nullptr);
    // T4 = AAT x1
    dmv(T3,  U4, T4, 0, nullptr, nullptr);

    // mid: largest = <T4, x1>/<x1,x1>;  Y = T4 - largest * x1
    {
        float a4 = (tid < CC) ? T3[tid] : 0.0f;
        float ss4 = blk_reduce16(a4 * a4, red);
        float rn4 = 1.0f / fmaxf(sqrtf(ss4), FEPS);
        float b5 = (tid < CC) ? T4[tid] : 0.0f;
        float x1 = a4 * rn4;
        float num = blk_reduce16(b5 * x1, red);
        float den = blk_reduce16(x1 * x1, red);
        float largest = num / den;
        if (s == 0) Y[c] = T4[c] - largest * (T3[c] * rn4);
        if (stripe == 0 && tid == 0) acc[b * 4 + 0] = largest;
    }
    grid.sync();

    // w = AAT x2 (x2 = normalize(Y)); dotwx = <w,x2>, den2 = <x2,x2>
    dmv(Y, U5, Wb, 1, &acc[b * 4 + 1], &acc[b * 4 + 2]);

    // final: penalty = mean_b (largest/smallest - 1)^2
    if (blockIdx.x == 0 && tid < 64) {
        int bb = tid;
        float largest = acc[bb * 4 + 0];
        float dotwx   = acc[bb * 4 + 1];
        float den2    = acc[bb * 4 + 2];
        float tmp = (dotwx - largest * den2) / den2;
        float smallest = tmp + largest;
        float rr = largest / smallest - 1.0f;
        float pen = rr * rr;               // BETA = 1
        for (int off = 32; off; off >>= 1) pen += __shfl_down(pen, off, 64);
        if (bb == 0) out[0] = pen / (float)BB;
    }
}

extern "C" void kernel_launch(void* const* d_in, const int* in_sizes, int n_in,
                              void* d_out, int out_size, void* d_ws, size_t ws_size,
                              hipStream_t stream) {
    const float* A  = (const float*)d_in[0];
    const float* x0 = (const float*)d_in[1];
    float* out = (float*)d_out;
    float* ws  = (float*)d_ws;
    void* args[] = { (void*)&A, (void*)&x0, (void*)&out, (void*)&ws };
    hipLaunchCooperativeKernel((const void*)c_all, dim3(NBLK), dim3(TPB),
                               args, 0, stream);
}

// Round 7
// 615.077 us; speedup vs baseline: 2.2429x; 2.2429x over previous
//
#include <hip/hip_runtime.h>
#include <hip/hip_cooperative_groups.h>
#include <math.h>

namespace cg = cooperative_groups;

// OFPenalty round 7: A resident in registers+LDS, budgeted correctly.
// 256 blocks x 512 thr (8 waves/CU = 2/EU -> 256 VGPR cap). Block owns
// (batch, 128-row stripe) = 401 KB of A: chunks 0-1 of each row in VGPRs
// (32 float4/thread, statically indexed), chunk 2 + tail in 139 KB LDS.
// A read from HBM exactly once; 6 double-matvecs run from regs+LDS.
// R6 failed on VGPR spill (1024-thr block -> 128-reg cap) + LDS atomics.
// A: (64, 512, 28, 28) fp32 -> W: (64, 512, 784). x0: (64, 512, 1).

#define BB 64
#define CC 512
#define DD 784
#define NBLK 256
#define TPB  512
#define RPB  128
#define FEPS 1e-12f

#define FMA4(acc, a, s) { (acc).x += (a).x*(s); (acc).y += (a).y*(s); \
                          (acc).z += (a).z*(s); (acc).w += (a).w*(s); }

__device__ __forceinline__ float dot4(float4 a, float4 b) {
    return a.x*b.x + a.y*b.y + a.z*b.z + a.w*b.w;
}

__device__ __forceinline__ float blk_reduce8(float s, float* red) {
    for (int off = 32; off; off >>= 1) s += __shfl_down(s, off, 64);
    int w = threadIdx.x >> 6;
    if ((threadIdx.x & 63) == 0) red[w] = s;
    __syncthreads();
    float t = red[0]+red[1]+red[2]+red[3]+red[4]+red[5]+red[6]+red[7];
    __syncthreads();
    return t;
}

__global__ __launch_bounds__(TPB, 2)
void c_all(const float* __restrict__ A, const float* __restrict__ x0,
           float* __restrict__ out, float* __restrict__ ws) {
    __shared__ float  lds_c2[RPB * 272];   // per row: chunk2 256f + tail 16f
    __shared__ float4 u4s[196];            // u vector (784 floats)
    __shared__ float  xs[CC];
    __shared__ float  red[8];
    float* u_lds = (float*)u4s;
    cg::grid_group grid = cg::this_grid();

    const int tid = threadIdx.x;
    const int w  = tid >> 6, ln = tid & 63;
    const int b  = blockIdx.x >> 2, q = blockIdx.x & 3;
    const int c0 = q * RPB;

    float* acc  = ws;                      // 256 floats: b*4: 0 largest, 1 dotwx, 2 den2
    float* ubuf = ws + 256;                // 6 x BB*DD (atomic, zeroed)
    float* tbuf = ws + 256 + 6 * BB * DD;  // 7 x BB*CC (plain stores)

    // ---- zero atomic-accumulated globals
    for (int i = blockIdx.x * TPB + tid; i < 256 + 6 * BB * DD; i += NBLK * TPB)
        ws[i] = 0.0f;

    // ---- load stripe: wave w owns rows w*16..w*16+15 of this block's 128.
    // Per row (196 f4): lane ln holds f4[ln], f4[64+ln] in regs;
    // f4[128+ln] and tail f4[192+ln] (ln<4) go to LDS.
    const float4* Abase = (const float4*)(A + ((size_t)b * CC + c0) * DD);
    float4 a0[16], a1[16];
#pragma unroll
    for (int r = 0; r < 16; r++) {
        int rl = w * 16 + r;
        const float4* row = Abase + (size_t)rl * 196;
        a0[r] = row[ln];
        a1[r] = row[64 + ln];
        float4* l4 = (float4*)&lds_c2[rl * 272];
        l4[ln] = row[128 + ln];
        if (ln < 4) l4[64 + ln] = row[192 + ln];
    }
    grid.sync();

    // ---- fused double-matvec: tn = AAT * normalize(xg) from regs+LDS.
    // mode 1: also dotwx += <v, xhat>, den2 += |xhat|^2.
    auto dmv = [&](const float* xg, float* ug, float* tn, int mode,
                   float* s0, float* s1) {
        // normalize input (redundant per block)
        float xv = xg[tid];
        float ssv = blk_reduce8(xv * xv, red);
        float rn = 1.0f / fmaxf(sqrtf(ssv), FEPS);
        xs[tid] = xv * rn;
        __syncthreads();

        // phase u: per-lane partials over the wave's 16 rows
        float4 u0 = make_float4(0.f,0.f,0.f,0.f), u1 = u0, u2 = u0, ut = u0;
#pragma unroll
        for (int r = 0; r < 16; r++) {
            int rl = w * 16 + r;
            float xc = xs[c0 + rl];
            FMA4(u0, a0[r], xc);
            FMA4(u1, a1[r], xc);
            float4 c2 = ((float4*)&lds_c2[rl * 272])[ln];
            FMA4(u2, c2, xc);
            if (ln < 4) {
                float4 t4 = ((float4*)&lds_c2[rl * 272])[64 + ln];
                FMA4(ut, t4, xc);
            }
        }
        // sequential cross-wave accumulate into u4s (no atomics)
        for (int w2 = 0; w2 < 8; w2++) {
            if (w == w2) {
                if (w2 == 0) {
                    u4s[ln] = u0; u4s[64+ln] = u1; u4s[128+ln] = u2;
                    if (ln < 4) u4s[192+ln] = ut;
                } else {
                    float4 t;
                    t = u4s[ln];     t.x+=u0.x; t.y+=u0.y; t.z+=u0.z; t.w+=u0.w; u4s[ln] = t;
                    t = u4s[64+ln];  t.x+=u1.x; t.y+=u1.y; t.z+=u1.z; t.w+=u1.w; u4s[64+ln] = t;
                    t = u4s[128+ln]; t.x+=u2.x; t.y+=u2.y; t.z+=u2.z; t.w+=u2.w; u4s[128+ln] = t;
                    if (ln < 4) {
                        t = u4s[192+ln]; t.x+=ut.x; t.y+=ut.y; t.z+=ut.z; t.w+=ut.w; u4s[192+ln] = t;
                    }
                }
            }
            __syncthreads();
        }
        // cross-block (4 blocks per batch) via global atomics
        for (int i = tid; i < DD; i += TPB) atomicAdd(&ug[i], u_lds[i]);
        grid.sync();
        // read back full-batch u
        for (int i = tid; i < 196; i += TPB) u4s[i] = ((const float4*)ug)[i];
        __syncthreads();

        // phase v: v_c = <A[c,:], u> (regs x LDS, xor-reduce over 64 lanes)
        float4 v0 = u4s[ln], v1 = u4s[64+ln], v2 = u4s[128+ln];
        float4 vt = (ln < 4) ? u4s[192+ln] : make_float4(0.f,0.f,0.f,0.f);
        float vkeep = 0.0f;
#pragma unroll
        for (int r = 0; r < 16; r++) {
            int rl = w * 16 + r;
            float4 c2 = ((float4*)&lds_c2[rl * 272])[ln];
            float dot = dot4(a0[r], v0) + dot4(a1[r], v1) + dot4(c2, v2);
            if (ln < 4) dot += dot4(((float4*)&lds_c2[rl * 272])[64 + ln], vt);
            dot += __shfl_xor(dot, 1);
            dot += __shfl_xor(dot, 2);
            dot += __shfl_xor(dot, 4);
            dot += __shfl_xor(dot, 8);
            dot += __shfl_xor(dot, 16);
            dot += __shfl_xor(dot, 32);
            if (ln == r) vkeep = dot;
        }
        if (ln < 16) tn[c0 + w * 16 + ln] = vkeep;
        if (mode) {
            float p0 = 0.0f, p1 = 0.0f;
            if (ln < 16) {
                float xn = xs[c0 + w * 16 + ln];
                p0 = vkeep * xn; p1 = xn * xn;
            }
            float P0 = blk_reduce8(p0, red);
            float P1 = blk_reduce8(p1, red);
            if (tid == 0) { atomicAdd(s0, P0); atomicAdd(s1, P1); }
        }
        grid.sync();
    };

    const float* x0b = x0 + (size_t)b * CC;
    float* T0 = tbuf + 0 * BB * CC + (size_t)b * CC;
    float* T1 = tbuf + 1 * BB * CC + (size_t)b * CC;
    float* T2 = tbuf + 2 * BB * CC + (size_t)b * CC;
    float* T3 = tbuf + 3 * BB * CC + (size_t)b * CC;  // unnormalized x1
    float* T4 = tbuf + 4 * BB * CC + (size_t)b * CC;  // AAT x1
    float* Y  = tbuf + 5 * BB * CC + (size_t)b * CC;  // unnormalized x2
    float* Wb = tbuf + 6 * BB * CC + (size_t)b * CC;
    float* U0 = ubuf + 0 * BB * DD + (size_t)b * DD;
    float* U1 = ubuf + 1 * BB * DD + (size_t)b * DD;
    float* U2 = ubuf + 2 * BB * DD + (size_t)b * DD;
    float* U3 = ubuf + 3 * BB * DD + (size_t)b * DD;
    float* U4 = ubuf + 4 * BB * DD + (size_t)b * DD;
    float* U5 = ubuf + 5 * BB * DD + (size_t)b * DD;

    dmv(x0b, U0, T0, 0, nullptr, nullptr);
    dmv(T0,  U1, T1, 0, nullptr, nullptr);
    dmv(T1,  U2, T2, 0, nullptr, nullptr);
    dmv(T2,  U3, T3, 0, nullptr, nullptr);
    dmv(T3,  U4, T4, 0, nullptr, nullptr);

    // mid: largest = <T4,x1>/<x1,x1>, x1 = normalize(T3); Y = T4 - largest*x1
    {
        float a4 = T3[tid];
        float ss4 = blk_reduce8(a4 * a4, red);
        float rn4 = 1.0f / fmaxf(sqrtf(ss4), FEPS);
        float b5 = T4[tid];
        float x1 = a4 * rn4;
        float num = blk_reduce8(b5 * x1, red);
        float den = blk_reduce8(x1 * x1, red);
        float largest = num / den;
        if (tid >= c0 && tid < c0 + RPB)
            Y[tid] = T4[tid] - largest * (T3[tid] * rn4);
        if (q == 0 && tid == 0) acc[b * 4 + 0] = largest;
    }
    grid.sync();

    // w = AAT x2, x2 = normalize(Y); dotwx = <w,x2>, den2 = <x2,x2>
    dmv(Y, U5, Wb, 1, &acc[b * 4 + 1], &acc[b * 4 + 2]);

    // final: penalty = mean_b (largest/smallest - 1)^2
    if (blockIdx.x == 0 && tid < 64) {
        int bb = tid;
        float largest = acc[bb * 4 + 0];
        float dotwx   = acc[bb * 4 + 1];
        float den2    = acc[bb * 4 + 2];
        float tmp = (dotwx - largest * den2) / den2;
        float smallest = tmp + largest;
        float rr = largest / smallest - 1.0f;
        float pen = rr * rr;               // BETA = 1
        for (int off = 32; off; off >>= 1) pen += __shfl_down(pen, off, 64);
        if (bb == 0) out[0] = pen / (float)BB;
    }
}

// ======================= fallback: round-3 multi-launch =======================
#define STRIPES 16
#define RPS 32

__global__ void f_zero(float* __restrict__ p, int n) {
    int i = blockIdx.x * 256 + threadIdx.x;
    if (i < n) p[i] = 0.0f;
}

__device__ __forceinline__ float f_blk_reduce(float s, float* red) {
    for (int off = 32; off; off >>= 1) s += __shfl_down(s, off, 64);
    int w = threadIdx.x >> 6;
    if ((threadIdx.x & 63) == 0) red[w] = s;
    __syncthreads();
    float t = red[0] + red[1] + red[2] + red[3];
    __syncthreads();
    return t;
}

__global__ void f_init(const float* __restrict__ x0, float* __restrict__ acc) {
    __shared__ float red[4];
    int b = blockIdx.x;
    const float* x = x0 + (size_t)b * CC;
    float v0 = x[threadIdx.x], v1 = x[threadIdx.x + 256];
    float t = f_blk_reduce(v0 * v0 + v1 * v1, red);
    if (threadIdx.x == 0) acc[b * 16 + 0] = t;
}

__global__ __launch_bounds__(256, 4)
void f_u(const float* __restrict__ A, const float* __restrict__ xin,
         const float* __restrict__ acc, int ss_k, float* __restrict__ uout) {
    __shared__ float up[4][800];
    int b = blockIdx.y, stripe = blockIdx.x;
    int wave = threadIdx.x >> 6, lane = threadIdx.x & 63;
    int c0 = stripe * RPS;
    float rn = 1.0f / fmaxf(sqrtf(acc[b * 16 + ss_k]), FEPS);
    const float* xp = xin + (size_t)b * CC;
    float xv[8];
#pragma unroll
    for (int i = 0; i < 8; i++) xv[i] = xp[c0 + wave + 4 * i] * rn;
    const float4* Abase = (const float4*)(A + ((size_t)b * CC + c0) * DD);
    float4 a0 = make_float4(0.f,0.f,0.f,0.f), a1 = a0, a2 = a0, a3 = a0;
#pragma unroll 4
    for (int i = 0; i < 8; i++) {
        const float4* row = Abase + (size_t)(wave + 4 * i) * 196;
        float xc = xv[i];
        float4 f0 = row[lane], f1 = row[lane + 64], f2 = row[lane + 128];
        FMA4(a0, f0, xc); FMA4(a1, f1, xc); FMA4(a2, f2, xc);
        if (lane < 4) { float4 f3 = row[192 + lane]; FMA4(a3, f3, xc); }
    }
    int d4 = 4 * lane;
    *(float4*)&up[wave][d4]       = a0;
    *(float4*)&up[wave][d4 + 256] = a1;
    *(float4*)&up[wave][d4 + 512] = a2;
    if (lane < 4) *(float4*)&up[wave][d4 + 768] = a3;
    __syncthreads();
    float* uo = uout + (size_t)b * DD;
    for (int d = threadIdx.x; d < DD; d += 256)
        atomicAdd(&uo[d], up[0][d] + up[1][d] + up[2][d] + up[3][d]);
}

__global__ void f_a(const float* __restrict__ A, const float* __restrict__ u,
                    float* __restrict__ vout, float* __restrict__ acc,
                    int mode, int k0,
                    const float* __restrict__ xvec2, int ss_k2) {
    int b = blockIdx.y;
    int wave = threadIdx.x >> 6, lane = threadIdx.x & 63;
    int c = blockIdx.x * 4 + wave;
    const float4* ap = (const float4*)(A + (size_t)(b * CC + c) * DD);
    const float4* up = (const float4*)(u + (size_t)b * DD);
    float s = 0.0f;
#pragma unroll
    for (int k = 0; k < 3; ++k)
        s += dot4(ap[lane + 64 * k], up[lane + 64 * k]);
    if (lane < 4) s += dot4(ap[192 + lane], up[192 + lane]);
    for (int off = 32; off; off >>= 1) s += __shfl_down(s, off, 64);
    __shared__ float p0[4], p1[4];
    if (lane == 0) {
        if (vout) vout[(size_t)b * CC + c] = s;
        if (mode == 0) { p0[wave] = s * s; p1[wave] = 0.0f; }
        else {
            float denom2 = fmaxf(sqrtf(acc[b * 16 + ss_k2]), FEPS);
            float xn = xvec2[(size_t)b * CC + c] / denom2;
            p0[wave] = s * xn; p1[wave] = xn * xn;
        }
    }
    __syncthreads();
    if (threadIdx.x == 0) {
        atomicAdd(&acc[b * 16 + k0], p0[0] + p0[1] + p0[2] + p0[3]);
        if (mode == 1)
            atomicAdd(&acc[b * 16 + k0 + 1], p1[0] + p1[1] + p1[2] + p1[3]);
    }
}

__global__ void f_mid(const float* __restrict__ t4, const float* __restrict__ t5,
                      float* __restrict__ acc, float* __restrict__ y) {
    __shared__ float red[4];
    int b = blockIdx.x;
    float num = acc[b * 16 + 5], den = acc[b * 16 + 6];
    float largest = num / den;
    float rn = 1.0f / fmaxf(sqrtf(acc[b * 16 + 4]), FEPS);
    const float* p4 = t4 + (size_t)b * CC;
    const float* p5 = t5 + (size_t)b * CC;
    float* yp = y + (size_t)b * CC;
    float a0 = p4[threadIdx.x], a1 = p4[threadIdx.x + 256];
    float b0 = p5[threadIdx.x], b1 = p5[threadIdx.x + 256];
    float y0 = b0 - largest * (a0 * rn);
    float y1 = b1 - largest * (a1 * rn);
    yp[threadIdx.x] = y0;
    yp[threadIdx.x + 256] = y1;
    float t = f_blk_reduce(y0 * y0 + y1 * y1, red);
    if (threadIdx.x == 0) { acc[b * 16 + 7] = t; acc[b * 16 + 8] = largest; }
}

__global__ void f_out(const float* __restrict__ acc, float* __restrict__ out) {
    int b = threadIdx.x;
    float largest = acc[b * 16 + 8];
    float dotwx   = acc[b * 16 + 9];
    float den2    = acc[b * 16 + 10];
    float tmp = (dotwx - largest * den2) / den2;
    float smallest = tmp + largest;
    float r = largest / smallest - 1.0f;
    float pen = r * r;
    for (int off = 32; off; off >>= 1) pen += __shfl_down(pen, off, 64);
    if (b == 0) out[0] = pen / (float)BB;
}

extern "C" void kernel_launch(void* const* d_in, const int* in_sizes, int n_in,
                              void* d_out, int out_size, void* d_ws, size_t ws_size,
                              hipStream_t stream) {
    const float* A  = (const float*)d_in[0];
    const float* x0 = (const float*)d_in[1];
    float* out = (float*)d_out;
    float* ws  = (float*)d_ws;

    void* args[] = { (void*)&A, (void*)&x0, (void*)&out, (void*)&ws };
    hipError_t e = hipLaunchCooperativeKernel((const void*)c_all, dim3(NBLK),
                                              dim3(TPB), args, 0, stream);
    if (e == hipSuccess) return;

    // ---------- fallback: proven round-3 multi-launch path ----------
    float* acc = ws;
    float* u1  = ws + 1024;
    float* u2  = u1 + BB * DD;
    float* u3  = u2 + BB * DD;
    float* u4  = u3 + BB * DD;
    float* u5  = u4 + BB * DD;
    float* u6  = u5 + BB * DD;
    float* t1  = u6 + BB * DD;
    float* t2  = t1 + BB * CC;
    float* t3  = t2 + BB * CC;
    float* t4  = t3 + BB * CC;
    float* t5  = t4 + BB * CC;
    float* y   = t5 + BB * CC;

    int nz = 1024 + 6 * BB * DD;
    f_zero<<<(nz + 255) / 256, 256, 0, stream>>>(ws, nz);
    f_init<<<BB, 256, 0, stream>>>(x0, acc);

    dim3 gU(STRIPES, BB), gA(CC / 4, BB);
    f_u<<<gU, 256, 0, stream>>>(A, x0, acc, 0, u1);
    f_a<<<gA, 256, 0, stream>>>(A, u1, t1, acc, 0, 1, nullptr, 0);
    f_u<<<gU, 256, 0, stream>>>(A, t1, acc, 1, u2);
    f_a<<<gA, 256, 0, stream>>>(A, u2, t2, acc, 0, 2, nullptr, 0);
    f_u<<<gU, 256, 0, stream>>>(A, t2, acc, 2, u3);
    f_a<<<gA, 256, 0, stream>>>(A, u3, t3, acc, 0, 3, nullptr, 0);
    f_u<<<gU, 256, 0, stream>>>(A, t3, acc, 3, u4);
    f_a<<<gA, 256, 0, stream>>>(A, u4, t4, acc, 0, 4, nullptr, 0);
    f_u<<<gU, 256, 0, stream>>>(A, t4, acc, 4, u5);
    f_a<<<gA, 256, 0, stream>>>(A, u5, t5, acc, 1, 5, t4, 4);
    f_mid<<<BB, 256, 0, stream>>>(t4, t5, acc, y);
    f_u<<<gU, 256, 0, stream>>>(A, y, acc, 7, u6);
    f_a<<<gA, 256, 0, stream>>>(A, u6, nullptr, acc, 1, 9, y, 7);
    f_out<<<1, 64, 0, stream>>>(acc, out);
}